// Round 9
// baseline (596.077 us; speedup 1.0000x reference)
//
#include <hip/hip_runtime.h>
#include <hip/hip_bf16.h>

// G2AAgent — ROUND 17: kSeq occupancy experiment (512,8) + rotation revert.
//  R16 post-mortem: FAILED (+3us). Rotation was a reasoning error — with a
//  per-step barrier the critical path is max-over-waves EACH step; rotating
//  the 16-MFMA logit wave balances cumulative work (irrelevant) and added
//  branch/lacc bookkeeping to all 8 waves. Reverted; C-init extension kept.
//  This round's lever: kSeq resources allow 4 blocks/CU (LDS 36.9KBx4=147
//  <=160; VGPR 60x8=480<=512/SIMD) yet occupancy sat at 41% (~2 blocks/CU)
//  for six rounds. The one soft cap: my own __launch_bounds__(512,4).
//  Change to (512,8) — already at 60 VGPR so no spill expected. More
//  co-resident blocks hide the quarter-rate trans chains + 15 barrier
//  drains (when one block drains, another's waves issue).
//  Attribution: occupancy counter decides. 41->65+% => ~95-100us kSeq;
//  unchanged => 41% is a HW/scheduler cap, kSeq is at structural floor.

typedef __attribute__((ext_vector_type(8))) short short8;
typedef __attribute__((ext_vector_type(4))) short short4v;
typedef __attribute__((ext_vector_type(4))) float float4v;

#define BF2F(x) __bfloat162float(x)
typedef __hip_bfloat16 bf;

__device__ __forceinline__ float frcp(float x) {
  return __builtin_amdgcn_rcpf(x);
}
__device__ __forceinline__ float fsigmoid(float x) {
  return frcp(1.f + __expf(-x));
}
__device__ __forceinline__ float ftanh(float x) {
  float e = __expf(2.f * x);
  return 1.f - 2.f * frcp(1.f + e);
}
__device__ __forceinline__ float rdv(const void* p, int i, int f) {
  return f ? ((const float*)p)[i] : BF2F(((const bf*)p)[i]);
}

// ---------------------------------------------------------------------------
static const int AO[23] = {
  0, 2097152, 4194304, 4685824, 4702208, 4702336, 4751488, 4800640, 4801024,
  4801408, 4899712, 4948864, 4949248, 4949632, 5047936, 5097088, 5097472,
  5097856, 5098368, 5098384, 5102480, 5106576, 5110160};
static const int AN[23] = {
  2097152, 2097152, 491520, 16384, 128, 49152, 49152, 384, 384, 98304, 49152,
  384, 384, 98304, 49152, 384, 384, 512, 2, 4096, 4096, 3584, 14};

struct CArgs {
  const void* src[23];
  int n[23];
  int off[23];
};

// ---------------------------------------------------------------------------
// kConvert: per-block self-detect of input dtype; y<23 = vectorized
// normalize into arena (skips 2/18/22); y==23 = prep (Wqk/W2p/Wcb).
__global__ void kConvert(CArgs a, int* __restrict__ flagOut,
                         bf* __restrict__ arena,
                         const void* __restrict__ WqR, const void* __restrict__ WkR,
                         const void* __restrict__ W2R, const void* __restrict__ WcR,
                         bf* __restrict__ Wqk, bf* __restrict__ W2p,
                         bf* __restrict__ Wcb) {
  __shared__ int sflag;
  if (threadIdx.x == 0) sflag = 0;
  __syncthreads();
  {
    const unsigned short* p0 = (const unsigned short*)a.src[0];
    int hit = 0;
    for (int i = threadIdx.x; i < 1024; i += 256) {
      int e = (p0[i] >> 7) & 0xFF;
      if (e >= 0xC0) hit = 1;
    }
    if (hit) atomicOr(&sflag, 1);
  }
  __syncthreads();
  const int f = sflag;
  const int b = blockIdx.y;
  if (b == 0 && blockIdx.x == 0 && threadIdx.x == 0) *flagOut = f;

  if (b == 23) {  // prep
    int idx = blockIdx.x * 256 + threadIdx.x;
    if (idx < 8192) {
      int r = idx >> 7, c = idx & 127;
      float v = (r < 32) ? rdv(WqR, r * 128 + c, f) : rdv(WkR, (r - 32) * 128 + c, f);
      Wqk[idx] = __float2bfloat16(v);
    }
    if (idx < 4096)
      W2p[idx] = __float2bfloat16((idx < 3584) ? rdv(W2R, idx, f) : 0.f);
    if (idx < 512) {
      int dir = idx >> 8, l = (idx >> 7) & 1, k = idx & 127;
      Wcb[idx] = __float2bfloat16(rdv(WcR, l * 256 + dir * 128 + k, f));
    }
    return;
  }
  if (b == 2 || b == 18 || b == 22) return;  // consumed raw via rdv
  const int n = a.n[b];
  const int nv = n & ~7;
  bf* dst = arena + a.off[b];
  const int gid = blockIdx.x * 256 + threadIdx.x;
  const int gs = gridDim.x * 256;
  if (f) {
    const float* s = (const float*)a.src[b];
    for (int i = gid * 8; i < nv; i += gs * 8) {
      float4 x0 = *(const float4*)(s + i);
      float4 x1 = *(const float4*)(s + i + 4);
      short8 v;
      bf t;
      t = __float2bfloat16(x0.x); v[0] = *(short*)&t;
      t = __float2bfloat16(x0.y); v[1] = *(short*)&t;
      t = __float2bfloat16(x0.z); v[2] = *(short*)&t;
      t = __float2bfloat16(x0.w); v[3] = *(short*)&t;
      t = __float2bfloat16(x1.x); v[4] = *(short*)&t;
      t = __float2bfloat16(x1.y); v[5] = *(short*)&t;
      t = __float2bfloat16(x1.z); v[6] = *(short*)&t;
      t = __float2bfloat16(x1.w); v[7] = *(short*)&t;
      *(short8*)(dst + i) = v;
    }
    for (int i = nv + gid; i < n; i += gs) dst[i] = __float2bfloat16(s[i]);
  } else {
    const short8* s = (const short8*)a.src[b];
    short8* d = (short8*)dst;
    for (int i = gid; i * 8 < nv; i += gs) d[i] = s[i];
    const unsigned short* ss = (const unsigned short*)a.src[b];
    unsigned short* ds = (unsigned short*)dst;
    for (int i = nv + gid; i < n; i += gs) ds[i] = ss[i];
  }
}

// ---------------------------------------------------------------------------
// kPre: env-local fusion of x1 + gi_c + cell GRU. 1024 blocks x 16 rows.
__global__ __launch_bounds__(256) void kPre(
    const bf* __restrict__ inputs, const bf* __restrict__ W1,
    const bf* __restrict__ b1, const bf* __restrict__ Wih,
    const bf* __restrict__ bih, const bf* __restrict__ hidden,
    const bf* __restrict__ Whh, const bf* __restrict__ bhh,
    bf* __restrict__ hrnn, float* __restrict__ outh) {
  __shared__ bf sX[16][136];  // x1 tile, 4.25 KB
  const int tid = threadIdx.x;
  const int wave = tid >> 6, lane = tid & 63;
  const int quad = lane >> 4, ci = lane & 15;
  const int row0 = blockIdx.x * 16;

  // stage A: swapped -> D[x1col][row]; wave owns col-tiles {2w, 2w+1}.
  float4v xa[2];
#pragma unroll
  for (int i = 0; i < 2; ++i) xa[i] = {0.f, 0.f, 0.f, 0.f};
#pragma unroll
  for (int ks = 0; ks < 4; ++ks) {
    short8 inr = *(const short8*)(inputs + (size_t)(row0 + ci) * 128 + ks * 32 + quad * 8);
#pragma unroll
    for (int c2 = 0; c2 < 2; ++c2) {
      int ct = wave * 2 + c2;
      short8 wfr = *(const short8*)(W1 + (size_t)(ct * 16 + ci) * 128 + ks * 32 + quad * 8);
      xa[c2] = __builtin_amdgcn_mfma_f32_16x16x32_bf16(wfr, inr, xa[c2], 0, 0, 0);
    }
  }
#pragma unroll
  for (int c2 = 0; c2 < 2; ++c2) {
    int ct = wave * 2 + c2;
    short4v v4;
#pragma unroll
    for (int r = 0; r < 4; ++r) {
      float v = xa[c2][r] + BF2F(b1[ct * 16 + quad * 4 + r]);
      v = fmaxf(v, 0.f);
      bf t = __float2bfloat16(v);
      v4[r] = *(short*)&t;
    }
    *(short4v*)&sX[ci][ct * 16 + quad * 4] = v4;
  }
  __syncthreads();

  short8 af[4];
#pragma unroll
  for (int ks = 0; ks < 4; ++ks)
    af[ks] = *(const short8*)&sX[ci][ks * 32 + quad * 8];

  // stage B: gh + gi, standard D[row][col]; wave owns cols wave*32 + nt*16.
  float4v ah[6], ag[6];
#pragma unroll
  for (int i = 0; i < 6; ++i) { ah[i] = {0.f, 0.f, 0.f, 0.f}; ag[i] = {0.f, 0.f, 0.f, 0.f}; }
#pragma unroll
  for (int ks = 0; ks < 4; ++ks) {
    short8 hr = *(const short8*)(hidden + (size_t)(row0 + ci) * 128 + ks * 32 + quad * 8);
#pragma unroll
    for (int g = 0; g < 3; ++g)
#pragma unroll
      for (int nt = 0; nt < 2; ++nt) {
        int wrow = g * 128 + wave * 32 + nt * 16 + ci;
        short8 bw = *(const short8*)(Whh + (size_t)wrow * 128 + ks * 32 + quad * 8);
        ah[g * 2 + nt] = __builtin_amdgcn_mfma_f32_16x16x32_bf16(hr, bw, ah[g * 2 + nt], 0, 0, 0);
        short8 bi_ = *(const short8*)(Wih + (size_t)wrow * 128 + ks * 32 + quad * 8);
        ag[g * 2 + nt] = __builtin_amdgcn_mfma_f32_16x16x32_bf16(af[ks], bi_, ag[g * 2 + nt], 0, 0, 0);
      }
  }

#pragma unroll
  for (int nt = 0; nt < 2; ++nt) {
    int c = wave * 32 + nt * 16 + ci;
    float biR = BF2F(bih[c]),       bhR = BF2F(bhh[c]);
    float biZ = BF2F(bih[128 + c]), bhZ = BF2F(bhh[128 + c]);
    float biN = BF2F(bih[256 + c]), bhN = BF2F(bhh[256 + c]);
#pragma unroll
    for (int r = 0; r < 4; ++r) {
      int rr = row0 + quad * 4 + r;
      float pre_r = ah[nt][r] + (ag[nt][r] + biR) + bhR;
      float pre_z = ah[2 + nt][r] + (ag[2 + nt][r] + biZ) + bhZ;
      float gnn   = ag[4 + nt][r] + biN;
      float hn_   = ah[4 + nt][r] + bhN;
      float rg = fsigmoid(pre_r);
      float zg = fsigmoid(pre_z);
      float ng = ftanh(gnn + rg * hn_);
      float hp = BF2F(hidden[(size_t)rr * 128 + c]);
      float hv = ng + zg * (hp - ng);
      hrnn[(size_t)rr * 128 + c] = __float2bfloat16(hv);
      outh[(size_t)rr * 128 + c] = hv;
    }
  }
}

// ---------------------------------------------------------------------------
// kSeq v10: grid (1024, 2), 512 thr = 8 waves, __launch_bounds__(512, 8)
// (occupancy experiment: resources allow 4 blocks/CU). Operand-swapped
// MFMAs; fp32 nbr-gi; C-init carries gS+nb (r,z) and bNc; logit MFMA on
// wave 0 (rotation reverted — per-step barrier makes rotation useless).
__global__ __launch_bounds__(512, 8) void kSeq(
    const bf* __restrict__ hrnn,
    const bf* __restrict__ Wih_f, const bf* __restrict__ Wih_b,
    const bf* __restrict__ Whh_f, const bf* __restrict__ Whh_b,
    const bf* __restrict__ bih_f, const bf* __restrict__ bih_b,
    const bf* __restrict__ bhh_f, const bf* __restrict__ bhh_b,
    const bf* __restrict__ Wcb, float* __restrict__ L) {
  __shared__ float sGiN[16][3][132];            // [batch][gate][hcol] fp32 25.3KB
  __shared__ bf sH[2][16][136];                 // h ping-pong [batch][hcol]
  __shared__ float sL[16][15][2];               // logits [batch][m][logit]
  __shared__ bf sWc[2][136];                    // Wc rows for this dir

  const int env = blockIdx.x;
  const int dir = blockIdx.y;
  const int tid = threadIdx.x;
  const int wave = tid >> 6, lane = tid & 63;
  const int nh = wave;
  const int quad = lane >> 4, ci = lane & 15;
  const bf* Wih = dir ? Wih_b : Wih_f;
  const bf* Whh = dir ? Whh_b : Whh_f;
  const bf* bih = dir ? bih_b : bih_f;
  const bf* bhh = dir ? bhh_b : bhh_f;
  const int h0q = nh * 16 + quad * 4;

  // ---- Phase 1: gi GEMM (swapped: D[hcol][batch]) ----
  float4v gS[3], gN[3];
#pragma unroll
  for (int i = 0; i < 3; ++i) { gS[i] = {0.f, 0.f, 0.f, 0.f}; gN[i] = {0.f, 0.f, 0.f, 0.f}; }
#pragma unroll
  for (int ks = 0; ks < 4; ++ks) {
    short8 bh = *(const short8*)(hrnn + (size_t)(env * 16 + ci) * 128 + ks * 32 + quad * 8);
#pragma unroll
    for (int g = 0; g < 3; ++g) {
      const bf* wrow = Wih + (size_t)(g * 128 + nh * 16 + ci) * 256 + ks * 32 + quad * 8;
      short8 ws = *(const short8*)(wrow);
      short8 wn = *(const short8*)(wrow + 128);
      gS[g] = __builtin_amdgcn_mfma_f32_16x16x32_bf16(ws, bh, gS[g], 0, 0, 0);
      gN[g] = __builtin_amdgcn_mfma_f32_16x16x32_bf16(wn, bh, gN[g], 0, 0, 0);
    }
  }
#pragma unroll
  for (int g = 0; g < 3; ++g)
#pragma unroll
    for (int r = 0; r < 4; ++r) {
      int c = g * 128 + h0q + r;
      float bv = BF2F(bih[c]);
      if (g < 2) bv += BF2F(bhh[c]);
      gS[g][r] += bv;
    }
  // nbr-gi straight to LDS as fp32 (one b128 store per gate)
#pragma unroll
  for (int g = 0; g < 3; ++g)
    *(float4v*)&sGiN[ci][g][h0q] = gN[g];

  {
    bf z = __float2bfloat16(0.f);
    bf* p = &sH[0][0][0];
    for (int i = tid; i < 16 * 136; i += 512) p[i] = z;
    if (tid < 256)
      sWc[tid >> 7][tid & 127] = Wcb[(dir * 2 + (tid >> 7)) * 128 + (tid & 127)];
  }

  // ---- Phase 2: persistent Whh A-frags, constants ----
  short8 Bf[12];
#pragma unroll
  for (int g = 0; g < 3; ++g)
#pragma unroll
    for (int ks = 0; ks < 4; ++ks)
      Bf[g * 4 + ks] =
          *(const short8*)(Whh + (size_t)(g * 128 + nh * 16 + ci) * 128 + ks * 32 + quad * 8);

  float4v bNcV;
#pragma unroll
  for (int r = 0; r < 4; ++r) bNcV[r] = BF2F(bhh[256 + h0q + r]);

  float hPrev[4];
#pragma unroll
  for (int r = 0; r < 4; ++r) hPrev[r] = 0.f;

  __syncthreads();

  // ---- Phase 3: 15 steps ----
  for (int t = 0; t < 15; ++t) {
    const int cur = t & 1, nxt = cur ^ 1;
    const int m = dir ? (14 - t) : t;
    const int jr = m + ((m >= ci) ? 1 : 0);

    float4v nbR = *(const float4v*)&sGiN[jr][0][h0q];
    float4v nbZ = *(const float4v*)&sGiN[jr][1][h0q];
    float4v nbN = *(const float4v*)&sGiN[jr][2][h0q];

    // C-init: MFMA chain carries gS+nb (r,z) and bhh_n; gnn hoisted.
    float4v acc[3];
    float gnnV[4];
#pragma unroll
    for (int r = 0; r < 4; ++r) {
      acc[0][r] = gS[0][r] + nbR[r];
      acc[1][r] = gS[1][r] + nbZ[r];
      gnnV[r]   = gS[2][r] + nbN[r];
    }
    acc[2] = bNcV;
    float4v lacc = {0.f, 0.f, 0.f, 0.f};
#pragma unroll
    for (int ks = 0; ks < 4; ++ks) {
      short8 bh = *(const short8*)&sH[cur][ci][ks * 32 + quad * 8];
#pragma unroll
      for (int g = 0; g < 3; ++g)
        acc[g] = __builtin_amdgcn_mfma_f32_16x16x32_bf16(Bf[g * 4 + ks], bh, acc[g], 0, 0, 0);
      if (nh == 0) {
        short8 wv = *(const short8*)&sWc[ci & 1][ks * 32 + quad * 8];
        lacc = __builtin_amdgcn_mfma_f32_16x16x32_bf16(wv, bh, lacc, 0, 0, 0);
      }
    }
    if (nh == 0 && t > 0 && quad == 0) {
      int mp = dir ? (15 - t) : (t - 1);
      sL[ci][mp][0] = lacc[0];
      sL[ci][mp][1] = lacc[1];
    }

    short4v hv4;
#pragma unroll
    for (int r = 0; r < 4; ++r) {
      float pre_r = acc[0][r];
      float pre_z = acc[1][r];
      float hn_   = acc[2][r];
      float rg = fsigmoid(pre_r);
      float zg = fsigmoid(pre_z);
      float ng = ftanh(gnnV[r] + rg * hn_);
      float hv = ng + zg * (hPrev[r] - ng);
      hPrev[r] = hv;
      bf b = __float2bfloat16(hv);
      hv4[r] = *(short*)&b;
    }
    *(short4v*)&sH[nxt][ci][h0q] = hv4;
    __syncthreads();
  }

  if (nh == 0) {
    float4v lacc = {0.f, 0.f, 0.f, 0.f};
#pragma unroll
    for (int ks = 0; ks < 4; ++ks) {
      short8 bh = *(const short8*)&sH[1][ci][ks * 32 + quad * 8];
      short8 wv = *(const short8*)&sWc[ci & 1][ks * 32 + quad * 8];
      lacc = __builtin_amdgcn_mfma_f32_16x16x32_bf16(wv, bh, lacc, 0, 0, 0);
    }
    if (quad == 0) {
      int mf = dir ? 0 : 14;
      sL[ci][mf][0] = lacc[0];
      sL[ci][mf][1] = lacc[1];
    }
  }
  __syncthreads();

  {
    float* Ld = L + (size_t)dir * 491520 + (size_t)env * 480;
    for (int i = tid; i < 480; i += 512) {
      int row = i / 30, rem = i - row * 30;
      int mm = rem >> 1, l = rem & 1;
      Ld[i] = sL[row][mm][l];
    }
  }
}

// ---------------------------------------------------------------------------
// kTail: 1024 blocks x 1 env. qk MFMA + gumbel + attn -> sAgg (LDS),
// then out14 GEMM (wave 0) for this env's 16 rows.
__global__ __launch_bounds__(256) void kTail(
    const bf* __restrict__ h, const bf* __restrict__ Wqk,
    const float* __restrict__ L, const void* __restrict__ guRaw,
    const void* __restrict__ bcRaw, const int* __restrict__ flag,
    const bf* __restrict__ W2p, const void* __restrict__ b2Raw,
    float* __restrict__ out) {
  __shared__ float sh[16 * 132];
  __shared__ float sqk[16 * 64];
  __shared__ float shw[240];
  __shared__ float sw[16 * 16];
  __shared__ bf sAgg[16][136];
  const int bb = blockIdx.x;
  const int tid = threadIdx.x;
  const int f = *flag;
  const int a = tid >> 4, i = tid & 15;

  {
    const int w = tid >> 6, lane = tid & 63;
    const int quad = lane >> 4, ci = lane & 15;
    float4v acc = {0.f, 0.f, 0.f, 0.f};
#pragma unroll
    for (int ks = 0; ks < 4; ++ks) {
      short8 a_ = *(const short8*)(h + (size_t)(bb * 16 + ci) * 128 + ks * 32 + quad * 8);
      short8 b_ = *(const short8*)(Wqk + (size_t)(w * 16 + ci) * 128 + ks * 32 + quad * 8);
      acc = __builtin_amdgcn_mfma_f32_16x16x32_bf16(a_, b_, acc, 0, 0, 0);
    }
#pragma unroll
    for (int r = 0; r < 4; ++r)
      sqk[(quad * 4 + r) * 64 + w * 16 + ci] = acc[r];
  }
  {
    // vectorized h staging: one short8 per thread (row = tid>>4, col = (tid&15)*8)
    short8 hv = *(const short8*)(h + (size_t)bb * 2048 + tid * 8);
    int row = tid >> 4, col = (tid & 15) * 8;
    float* dst = &sh[row * 132 + col];
#pragma unroll
    for (int d = 0; d < 8; ++d) {
      unsigned short u = (unsigned short)hv[d];
      dst[d] = BF2F(*(const bf*)&u);
    }
  }
  if (tid < 240) {
    int idx = bb * 240 + tid;
    float l0 = L[(size_t)idx * 2]     + L[491520 + (size_t)idx * 2]     + rdv(bcRaw, 0, f);
    float l1 = L[(size_t)idx * 2 + 1] + L[491520 + (size_t)idx * 2 + 1] + rdv(bcRaw, 1, f);
    float u0 = rdv(guRaw, idx * 2, f);
    float u1 = rdv(guRaw, idx * 2 + 1, f);
    float g0 = -__logf(-__logf(u0 + 1e-10f) + 1e-10f);
    float g1 = -__logf(-__logf(u1 + 1e-10f) + 1e-10f);
    shw[tid] = fsigmoid(((l1 + g1) - (l0 + g0)) * 2.0f);
  }
  __syncthreads();

  float s = -1e30f;
  if (i < 15) {
    int j = i + (i >= a);
    float d = 0.f;
#pragma unroll
    for (int c = 0; c < 32; ++c) d += sqk[a * 64 + c] * sqk[j * 64 + 32 + c];
    s = shw[a * 15 + i] * d * 0.17677669529663687f;
  }
  float mx = s;
#pragma unroll
  for (int d = 1; d < 16; d <<= 1) mx = fmaxf(mx, __shfl_xor(mx, d));
  float ex = (i < 15) ? __expf(s - mx) : 0.f;
  float sum = ex;
#pragma unroll
  for (int d = 1; d < 16; d <<= 1) sum += __shfl_xor(sum, d);
  float w = (i < 15) ? (ex * frcp(sum)) * shw[a * 15 + i] : 0.f;
  sw[a * 16 + i] = w;
  __syncthreads();

  float ac[8] = {0, 0, 0, 0, 0, 0, 0, 0};
  for (int mm = 0; mm < 15; ++mm) {
    int jm = mm + (mm >= a);
    float wm = sw[a * 16 + mm];
    const float* shp = &sh[jm * 132 + i * 8];
    float4 h0 = *(const float4*)shp;
    float4 h1 = *(const float4*)(shp + 4);
    ac[0] += wm * h0.x; ac[1] += wm * h0.y; ac[2] += wm * h0.z; ac[3] += wm * h0.w;
    ac[4] += wm * h1.x; ac[5] += wm * h1.y; ac[6] += wm * h1.z; ac[7] += wm * h1.w;
  }
  short8 v;
#pragma unroll
  for (int d = 0; d < 8; ++d) {
    bf b = __float2bfloat16(ac[d]);
    v[d] = *(short*)&b;
  }
  *(short8*)&sAgg[a][i * 8] = v;
  __syncthreads();

  // out14 GEMM for this env's 16 rows (wave 0)
  if (tid < 64) {
    const int quad = tid >> 4, ci = tid & 15;
    const int mr = bb * 16;
    float4v acc = {0.f, 0.f, 0.f, 0.f};
#pragma unroll
    for (int ks = 0; ks < 4; ++ks) {
      short8 a_ = *(const short8*)(h + (size_t)(mr + ci) * 128 + ks * 32 + quad * 8);
      short8 b_ = *(const short8*)(W2p + (size_t)ci * 256 + ks * 32 + quad * 8);
      acc = __builtin_amdgcn_mfma_f32_16x16x32_bf16(a_, b_, acc, 0, 0, 0);
    }
#pragma unroll
    for (int ks = 0; ks < 4; ++ks) {
      short8 a_ = *(const short8*)&sAgg[ci][ks * 32 + quad * 8];
      short8 b_ = *(const short8*)(W2p + (size_t)ci * 256 + 128 + ks * 32 + quad * 8);
      acc = __builtin_amdgcn_mfma_f32_16x16x32_bf16(a_, b_, acc, 0, 0, 0);
    }
    if (ci < 14) {
      float bv = rdv(b2Raw, ci, f);
#pragma unroll
      for (int r = 0; r < 4; ++r)
        out[(size_t)(mr + quad * 4 + r) * 14 + ci] = acc[r] + bv;
    }
  }
}

// ---------------------------------------------------------------------------
extern "C" void kernel_launch(void* const* d_in, const int* in_sizes, int n_in,
                              void* d_out, int out_size, void* d_ws, size_t ws_size,
                              hipStream_t stream) {
  const size_t OFF_ARENA = 0;          // bf16 arena; L (3.93MB) overlaps dead
                                       //   inputs+hidden [0, 8.38MB) after kPre
  const size_t OFF_FLAG  = 10220544;
  const size_t OFF_WQK   = 26998016;   // 16 KB
  const size_t OFF_WCB   = 27014400;   // 1 KB
  const size_t OFF_W2P   = 27410944;   // 8 KB
  const size_t OFF_HRNN  = 27419136;   // 4 MB
  const size_t NEEDED    = 84042240;
  if (ws_size < NEEDED) return;
  if (n_in < 23 || in_sizes[0] != 2097152 || in_sizes[3] != 16384 ||
      in_sizes[5] != 49152 || in_sizes[9] != 98304 || in_sizes[17] != 512 ||
      in_sizes[19] != 4096 || in_sizes[21] != 3584 || out_size != 2326528)
    return;

  char* ws = (char*)d_ws;
  bf*    arena = (bf*)(ws + OFF_ARENA);
  float* L     = (float*)(ws + OFF_ARENA);  // 3.93 MB; valid after kPre
  int*   flag  = (int*)(ws + OFF_FLAG);
  bf*    Wqk   = (bf*)(ws + OFF_WQK);
  bf*    Wcb   = (bf*)(ws + OFF_WCB);
  bf*    W2p   = (bf*)(ws + OFF_W2P);
  bf*    hrnn  = (bf*)(ws + OFF_HRNN);

  float* out14 = (float*)d_out;
  float* outh  = (float*)d_out + 229376;

  CArgs ca;
  for (int i = 0; i < 23; ++i) { ca.src[i] = d_in[i]; ca.n[i] = AN[i]; ca.off[i] = AO[i]; }
  kConvert<<<dim3(128, 24), 256, 0, stream>>>(ca, flag, arena,
                                              d_in[19], d_in[20], d_in[21], d_in[17],
                                              Wqk, W2p, Wcb);

  const bf* inputs = arena + AO[0];
  const bf* hidden = arena + AO[1];
  const bf* W1     = arena + AO[3];
  const bf* b1     = arena + AO[4];
  const bf* Wih_c  = arena + AO[5];
  const bf* Whh_c  = arena + AO[6];
  const bf* bih_c  = arena + AO[7];
  const bf* bhh_c  = arena + AO[8];
  const bf* Wih_f  = arena + AO[9];
  const bf* Whh_f  = arena + AO[10];
  const bf* bih_f  = arena + AO[11];
  const bf* bhh_f  = arena + AO[12];
  const bf* Wih_b  = arena + AO[13];
  const bf* Whh_b  = arena + AO[14];
  const bf* bih_b  = arena + AO[15];
  const bf* bhh_b  = arena + AO[16];

  // fused x1 + gi_c + cell GRU (env-local, 1024 blocks)
  kPre<<<dim3(1024), 256, 0, stream>>>(inputs, W1, b1, Wih_c, bih_c, hidden,
                                       Whh_c, bhh_c, hrnn, outh);
  // fused gi-GEMM + 15-step bidirectional GRU -> L (2 dir planes)
  kSeq<<<dim3(1024, 2), 512, 0, stream>>>(hrnn, Wih_f, Wih_b, Whh_f, Whh_b,
                                          bih_f, bih_b, bhh_f, bhh_b, Wcb, L);
  // fused qk + gumbel + attention + out14 GEMM (1024 blocks)
  kTail<<<dim3(1024), 256, 0, stream>>>(hrnn, Wqk, L, d_in[2], d_in[18], flag,
                                        W2p, d_in[22], out14);
}

// Round 10
// 264.617 us; speedup vs baseline: 2.2526x; 2.2526x over previous
//
#include <hip/hip_runtime.h>
#include <hip/hip_bf16.h>

// G2AAgent — ROUND 18: revert launch_bounds to (512,4).
//  R17 post-mortem: (512,8) forced a 64-reg unified budget -> Bf/acc
//  spilled to scratch (VGPR 32, FETCH 1.26GB/dispatch, kSeq 447us).
//  Occupancy DID hit 87% — mechanism works, kernel doesn't fit. Root
//  understanding: CSV VGPR_Count=60 is arch-VGPRs; unified file total
//  ~120-128/wave (acc+gS+gN+Bf) -> 4 waves/SIMD is the true fit; 41%
//  occupancy was correct all along. Raising it needs Bf->LDS (-48 regs),
//  re-adding 12 ds_read/step — the R7-era regression path. kSeq ~114us is
//  this design's structural floor: ~47% VALU (3 irreducible sigmoid/tanh
//  per elem at quarter rate) + 20% MFMA + 15 barrier drains.
//  This round: ONLY the launch_bounds revert; rest = best verified config
//  (C-init v2, wave-0 logit, R16 kTail/kConvert). If this lands ~260us as
//  predicted, both ledgers are closed -> roofline call next.

typedef __attribute__((ext_vector_type(8))) short short8;
typedef __attribute__((ext_vector_type(4))) short short4v;
typedef __attribute__((ext_vector_type(4))) float float4v;

#define BF2F(x) __bfloat162float(x)
typedef __hip_bfloat16 bf;

__device__ __forceinline__ float frcp(float x) {
  return __builtin_amdgcn_rcpf(x);
}
__device__ __forceinline__ float fsigmoid(float x) {
  return frcp(1.f + __expf(-x));
}
__device__ __forceinline__ float ftanh(float x) {
  float e = __expf(2.f * x);
  return 1.f - 2.f * frcp(1.f + e);
}
__device__ __forceinline__ float rdv(const void* p, int i, int f) {
  return f ? ((const float*)p)[i] : BF2F(((const bf*)p)[i]);
}

// ---------------------------------------------------------------------------
static const int AO[23] = {
  0, 2097152, 4194304, 4685824, 4702208, 4702336, 4751488, 4800640, 4801024,
  4801408, 4899712, 4948864, 4949248, 4949632, 5047936, 5097088, 5097472,
  5097856, 5098368, 5098384, 5102480, 5106576, 5110160};
static const int AN[23] = {
  2097152, 2097152, 491520, 16384, 128, 49152, 49152, 384, 384, 98304, 49152,
  384, 384, 98304, 49152, 384, 384, 512, 2, 4096, 4096, 3584, 14};

struct CArgs {
  const void* src[23];
  int n[23];
  int off[23];
};

// ---------------------------------------------------------------------------
// kConvert: per-block self-detect of input dtype; y<23 = vectorized
// normalize into arena (skips 2/18/22); y==23 = prep (Wqk/W2p/Wcb).
__global__ void kConvert(CArgs a, int* __restrict__ flagOut,
                         bf* __restrict__ arena,
                         const void* __restrict__ WqR, const void* __restrict__ WkR,
                         const void* __restrict__ W2R, const void* __restrict__ WcR,
                         bf* __restrict__ Wqk, bf* __restrict__ W2p,
                         bf* __restrict__ Wcb) {
  __shared__ int sflag;
  if (threadIdx.x == 0) sflag = 0;
  __syncthreads();
  {
    const unsigned short* p0 = (const unsigned short*)a.src[0];
    int hit = 0;
    for (int i = threadIdx.x; i < 1024; i += 256) {
      int e = (p0[i] >> 7) & 0xFF;
      if (e >= 0xC0) hit = 1;
    }
    if (hit) atomicOr(&sflag, 1);
  }
  __syncthreads();
  const int f = sflag;
  const int b = blockIdx.y;
  if (b == 0 && blockIdx.x == 0 && threadIdx.x == 0) *flagOut = f;

  if (b == 23) {  // prep
    int idx = blockIdx.x * 256 + threadIdx.x;
    if (idx < 8192) {
      int r = idx >> 7, c = idx & 127;
      float v = (r < 32) ? rdv(WqR, r * 128 + c, f) : rdv(WkR, (r - 32) * 128 + c, f);
      Wqk[idx] = __float2bfloat16(v);
    }
    if (idx < 4096)
      W2p[idx] = __float2bfloat16((idx < 3584) ? rdv(W2R, idx, f) : 0.f);
    if (idx < 512) {
      int dir = idx >> 8, l = (idx >> 7) & 1, k = idx & 127;
      Wcb[idx] = __float2bfloat16(rdv(WcR, l * 256 + dir * 128 + k, f));
    }
    return;
  }
  if (b == 2 || b == 18 || b == 22) return;  // consumed raw via rdv
  const int n = a.n[b];
  const int nv = n & ~7;
  bf* dst = arena + a.off[b];
  const int gid = blockIdx.x * 256 + threadIdx.x;
  const int gs = gridDim.x * 256;
  if (f) {
    const float* s = (const float*)a.src[b];
    for (int i = gid * 8; i < nv; i += gs * 8) {
      float4 x0 = *(const float4*)(s + i);
      float4 x1 = *(const float4*)(s + i + 4);
      short8 v;
      bf t;
      t = __float2bfloat16(x0.x); v[0] = *(short*)&t;
      t = __float2bfloat16(x0.y); v[1] = *(short*)&t;
      t = __float2bfloat16(x0.z); v[2] = *(short*)&t;
      t = __float2bfloat16(x0.w); v[3] = *(short*)&t;
      t = __float2bfloat16(x1.x); v[4] = *(short*)&t;
      t = __float2bfloat16(x1.y); v[5] = *(short*)&t;
      t = __float2bfloat16(x1.z); v[6] = *(short*)&t;
      t = __float2bfloat16(x1.w); v[7] = *(short*)&t;
      *(short8*)(dst + i) = v;
    }
    for (int i = nv + gid; i < n; i += gs) dst[i] = __float2bfloat16(s[i]);
  } else {
    const short8* s = (const short8*)a.src[b];
    short8* d = (short8*)dst;
    for (int i = gid; i * 8 < nv; i += gs) d[i] = s[i];
    const unsigned short* ss = (const unsigned short*)a.src[b];
    unsigned short* ds = (unsigned short*)dst;
    for (int i = nv + gid; i < n; i += gs) ds[i] = ss[i];
  }
}

// ---------------------------------------------------------------------------
// kPre: env-local fusion of x1 + gi_c + cell GRU. 1024 blocks x 16 rows.
__global__ __launch_bounds__(256) void kPre(
    const bf* __restrict__ inputs, const bf* __restrict__ W1,
    const bf* __restrict__ b1, const bf* __restrict__ Wih,
    const bf* __restrict__ bih, const bf* __restrict__ hidden,
    const bf* __restrict__ Whh, const bf* __restrict__ bhh,
    bf* __restrict__ hrnn, float* __restrict__ outh) {
  __shared__ bf sX[16][136];  // x1 tile, 4.25 KB
  const int tid = threadIdx.x;
  const int wave = tid >> 6, lane = tid & 63;
  const int quad = lane >> 4, ci = lane & 15;
  const int row0 = blockIdx.x * 16;

  // stage A: swapped -> D[x1col][row]; wave owns col-tiles {2w, 2w+1}.
  float4v xa[2];
#pragma unroll
  for (int i = 0; i < 2; ++i) xa[i] = {0.f, 0.f, 0.f, 0.f};
#pragma unroll
  for (int ks = 0; ks < 4; ++ks) {
    short8 inr = *(const short8*)(inputs + (size_t)(row0 + ci) * 128 + ks * 32 + quad * 8);
#pragma unroll
    for (int c2 = 0; c2 < 2; ++c2) {
      int ct = wave * 2 + c2;
      short8 wfr = *(const short8*)(W1 + (size_t)(ct * 16 + ci) * 128 + ks * 32 + quad * 8);
      xa[c2] = __builtin_amdgcn_mfma_f32_16x16x32_bf16(wfr, inr, xa[c2], 0, 0, 0);
    }
  }
#pragma unroll
  for (int c2 = 0; c2 < 2; ++c2) {
    int ct = wave * 2 + c2;
    short4v v4;
#pragma unroll
    for (int r = 0; r < 4; ++r) {
      float v = xa[c2][r] + BF2F(b1[ct * 16 + quad * 4 + r]);
      v = fmaxf(v, 0.f);
      bf t = __float2bfloat16(v);
      v4[r] = *(short*)&t;
    }
    *(short4v*)&sX[ci][ct * 16 + quad * 4] = v4;
  }
  __syncthreads();

  short8 af[4];
#pragma unroll
  for (int ks = 0; ks < 4; ++ks)
    af[ks] = *(const short8*)&sX[ci][ks * 32 + quad * 8];

  // stage B: gh + gi, standard D[row][col]; wave owns cols wave*32 + nt*16.
  float4v ah[6], ag[6];
#pragma unroll
  for (int i = 0; i < 6; ++i) { ah[i] = {0.f, 0.f, 0.f, 0.f}; ag[i] = {0.f, 0.f, 0.f, 0.f}; }
#pragma unroll
  for (int ks = 0; ks < 4; ++ks) {
    short8 hr = *(const short8*)(hidden + (size_t)(row0 + ci) * 128 + ks * 32 + quad * 8);
#pragma unroll
    for (int g = 0; g < 3; ++g)
#pragma unroll
      for (int nt = 0; nt < 2; ++nt) {
        int wrow = g * 128 + wave * 32 + nt * 16 + ci;
        short8 bw = *(const short8*)(Whh + (size_t)wrow * 128 + ks * 32 + quad * 8);
        ah[g * 2 + nt] = __builtin_amdgcn_mfma_f32_16x16x32_bf16(hr, bw, ah[g * 2 + nt], 0, 0, 0);
        short8 bi_ = *(const short8*)(Wih + (size_t)wrow * 128 + ks * 32 + quad * 8);
        ag[g * 2 + nt] = __builtin_amdgcn_mfma_f32_16x16x32_bf16(af[ks], bi_, ag[g * 2 + nt], 0, 0, 0);
      }
  }

#pragma unroll
  for (int nt = 0; nt < 2; ++nt) {
    int c = wave * 32 + nt * 16 + ci;
    float biR = BF2F(bih[c]),       bhR = BF2F(bhh[c]);
    float biZ = BF2F(bih[128 + c]), bhZ = BF2F(bhh[128 + c]);
    float biN = BF2F(bih[256 + c]), bhN = BF2F(bhh[256 + c]);
#pragma unroll
    for (int r = 0; r < 4; ++r) {
      int rr = row0 + quad * 4 + r;
      float pre_r = ah[nt][r] + (ag[nt][r] + biR) + bhR;
      float pre_z = ah[2 + nt][r] + (ag[2 + nt][r] + biZ) + bhZ;
      float gnn   = ag[4 + nt][r] + biN;
      float hn_   = ah[4 + nt][r] + bhN;
      float rg = fsigmoid(pre_r);
      float zg = fsigmoid(pre_z);
      float ng = ftanh(gnn + rg * hn_);
      float hp = BF2F(hidden[(size_t)rr * 128 + c]);
      float hv = ng + zg * (hp - ng);
      hrnn[(size_t)rr * 128 + c] = __float2bfloat16(hv);
      outh[(size_t)rr * 128 + c] = hv;
    }
  }
}

// ---------------------------------------------------------------------------
// kSeq v11 (= v9 minus rotation, (512,4)): grid (1024, 2), 512 thr = 8 waves.
// Operand-swapped MFMAs; fp32 nbr-gi; C-init carries gS+nb (r,z) and bNc;
// logit MFMA on wave 0.
__global__ __launch_bounds__(512, 4) void kSeq(
    const bf* __restrict__ hrnn,
    const bf* __restrict__ Wih_f, const bf* __restrict__ Wih_b,
    const bf* __restrict__ Whh_f, const bf* __restrict__ Whh_b,
    const bf* __restrict__ bih_f, const bf* __restrict__ bih_b,
    const bf* __restrict__ bhh_f, const bf* __restrict__ bhh_b,
    const bf* __restrict__ Wcb, float* __restrict__ L) {
  __shared__ float sGiN[16][3][132];            // [batch][gate][hcol] fp32 25.3KB
  __shared__ bf sH[2][16][136];                 // h ping-pong [batch][hcol]
  __shared__ float sL[16][15][2];               // logits [batch][m][logit]
  __shared__ bf sWc[2][136];                    // Wc rows for this dir

  const int env = blockIdx.x;
  const int dir = blockIdx.y;
  const int tid = threadIdx.x;
  const int wave = tid >> 6, lane = tid & 63;
  const int nh = wave;
  const int quad = lane >> 4, ci = lane & 15;
  const bf* Wih = dir ? Wih_b : Wih_f;
  const bf* Whh = dir ? Whh_b : Whh_f;
  const bf* bih = dir ? bih_b : bih_f;
  const bf* bhh = dir ? bhh_b : bhh_f;
  const int h0q = nh * 16 + quad * 4;

  // ---- Phase 1: gi GEMM (swapped: D[hcol][batch]) ----
  float4v gS[3], gN[3];
#pragma unroll
  for (int i = 0; i < 3; ++i) { gS[i] = {0.f, 0.f, 0.f, 0.f}; gN[i] = {0.f, 0.f, 0.f, 0.f}; }
#pragma unroll
  for (int ks = 0; ks < 4; ++ks) {
    short8 bh = *(const short8*)(hrnn + (size_t)(env * 16 + ci) * 128 + ks * 32 + quad * 8);
#pragma unroll
    for (int g = 0; g < 3; ++g) {
      const bf* wrow = Wih + (size_t)(g * 128 + nh * 16 + ci) * 256 + ks * 32 + quad * 8;
      short8 ws = *(const short8*)(wrow);
      short8 wn = *(const short8*)(wrow + 128);
      gS[g] = __builtin_amdgcn_mfma_f32_16x16x32_bf16(ws, bh, gS[g], 0, 0, 0);
      gN[g] = __builtin_amdgcn_mfma_f32_16x16x32_bf16(wn, bh, gN[g], 0, 0, 0);
    }
  }
#pragma unroll
  for (int g = 0; g < 3; ++g)
#pragma unroll
    for (int r = 0; r < 4; ++r) {
      int c = g * 128 + h0q + r;
      float bv = BF2F(bih[c]);
      if (g < 2) bv += BF2F(bhh[c]);
      gS[g][r] += bv;
    }
  // nbr-gi straight to LDS as fp32 (one b128 store per gate)
#pragma unroll
  for (int g = 0; g < 3; ++g)
    *(float4v*)&sGiN[ci][g][h0q] = gN[g];

  {
    bf z = __float2bfloat16(0.f);
    bf* p = &sH[0][0][0];
    for (int i = tid; i < 16 * 136; i += 512) p[i] = z;
    if (tid < 256)
      sWc[tid >> 7][tid & 127] = Wcb[(dir * 2 + (tid >> 7)) * 128 + (tid & 127)];
  }

  // ---- Phase 2: persistent Whh A-frags, constants ----
  short8 Bf[12];
#pragma unroll
  for (int g = 0; g < 3; ++g)
#pragma unroll
    for (int ks = 0; ks < 4; ++ks)
      Bf[g * 4 + ks] =
          *(const short8*)(Whh + (size_t)(g * 128 + nh * 16 + ci) * 128 + ks * 32 + quad * 8);

  float4v bNcV;
#pragma unroll
  for (int r = 0; r < 4; ++r) bNcV[r] = BF2F(bhh[256 + h0q + r]);

  float hPrev[4];
#pragma unroll
  for (int r = 0; r < 4; ++r) hPrev[r] = 0.f;

  __syncthreads();

  // ---- Phase 3: 15 steps ----
  for (int t = 0; t < 15; ++t) {
    const int cur = t & 1, nxt = cur ^ 1;
    const int m = dir ? (14 - t) : t;
    const int jr = m + ((m >= ci) ? 1 : 0);

    float4v nbR = *(const float4v*)&sGiN[jr][0][h0q];
    float4v nbZ = *(const float4v*)&sGiN[jr][1][h0q];
    float4v nbN = *(const float4v*)&sGiN[jr][2][h0q];

    // C-init: MFMA chain carries gS+nb (r,z) and bhh_n; gnn hoisted.
    float4v acc[3];
    float gnnV[4];
#pragma unroll
    for (int r = 0; r < 4; ++r) {
      acc[0][r] = gS[0][r] + nbR[r];
      acc[1][r] = gS[1][r] + nbZ[r];
      gnnV[r]   = gS[2][r] + nbN[r];
    }
    acc[2] = bNcV;
    float4v lacc = {0.f, 0.f, 0.f, 0.f};
#pragma unroll
    for (int ks = 0; ks < 4; ++ks) {
      short8 bh = *(const short8*)&sH[cur][ci][ks * 32 + quad * 8];
#pragma unroll
      for (int g = 0; g < 3; ++g)
        acc[g] = __builtin_amdgcn_mfma_f32_16x16x32_bf16(Bf[g * 4 + ks], bh, acc[g], 0, 0, 0);
      if (nh == 0) {
        short8 wv = *(const short8*)&sWc[ci & 1][ks * 32 + quad * 8];
        lacc = __builtin_amdgcn_mfma_f32_16x16x32_bf16(wv, bh, lacc, 0, 0, 0);
      }
    }
    if (nh == 0 && t > 0 && quad == 0) {
      int mp = dir ? (15 - t) : (t - 1);
      sL[ci][mp][0] = lacc[0];
      sL[ci][mp][1] = lacc[1];
    }

    short4v hv4;
#pragma unroll
    for (int r = 0; r < 4; ++r) {
      float pre_r = acc[0][r];
      float pre_z = acc[1][r];
      float hn_   = acc[2][r];
      float rg = fsigmoid(pre_r);
      float zg = fsigmoid(pre_z);
      float ng = ftanh(gnnV[r] + rg * hn_);
      float hv = ng + zg * (hPrev[r] - ng);
      hPrev[r] = hv;
      bf b = __float2bfloat16(hv);
      hv4[r] = *(short*)&b;
    }
    *(short4v*)&sH[nxt][ci][h0q] = hv4;
    __syncthreads();
  }

  if (nh == 0) {
    float4v lacc = {0.f, 0.f, 0.f, 0.f};
#pragma unroll
    for (int ks = 0; ks < 4; ++ks) {
      short8 bh = *(const short8*)&sH[1][ci][ks * 32 + quad * 8];
      short8 wv = *(const short8*)&sWc[ci & 1][ks * 32 + quad * 8];
      lacc = __builtin_amdgcn_mfma_f32_16x16x32_bf16(wv, bh, lacc, 0, 0, 0);
    }
    if (quad == 0) {
      int mf = dir ? 0 : 14;
      sL[ci][mf][0] = lacc[0];
      sL[ci][mf][1] = lacc[1];
    }
  }
  __syncthreads();

  {
    float* Ld = L + (size_t)dir * 491520 + (size_t)env * 480;
    for (int i = tid; i < 480; i += 512) {
      int row = i / 30, rem = i - row * 30;
      int mm = rem >> 1, l = rem & 1;
      Ld[i] = sL[row][mm][l];
    }
  }
}

// ---------------------------------------------------------------------------
// kTail: 1024 blocks x 1 env. qk MFMA + gumbel + attn -> sAgg (LDS),
// then out14 GEMM (wave 0) for this env's 16 rows.
__global__ __launch_bounds__(256) void kTail(
    const bf* __restrict__ h, const bf* __restrict__ Wqk,
    const float* __restrict__ L, const void* __restrict__ guRaw,
    const void* __restrict__ bcRaw, const int* __restrict__ flag,
    const bf* __restrict__ W2p, const void* __restrict__ b2Raw,
    float* __restrict__ out) {
  __shared__ float sh[16 * 132];
  __shared__ float sqk[16 * 64];
  __shared__ float shw[240];
  __shared__ float sw[16 * 16];
  __shared__ bf sAgg[16][136];
  const int bb = blockIdx.x;
  const int tid = threadIdx.x;
  const int f = *flag;
  const int a = tid >> 4, i = tid & 15;

  {
    const int w = tid >> 6, lane = tid & 63;
    const int quad = lane >> 4, ci = lane & 15;
    float4v acc = {0.f, 0.f, 0.f, 0.f};
#pragma unroll
    for (int ks = 0; ks < 4; ++ks) {
      short8 a_ = *(const short8*)(h + (size_t)(bb * 16 + ci) * 128 + ks * 32 + quad * 8);
      short8 b_ = *(const short8*)(Wqk + (size_t)(w * 16 + ci) * 128 + ks * 32 + quad * 8);
      acc = __builtin_amdgcn_mfma_f32_16x16x32_bf16(a_, b_, acc, 0, 0, 0);
    }
#pragma unroll
    for (int r = 0; r < 4; ++r)
      sqk[(quad * 4 + r) * 64 + w * 16 + ci] = acc[r];
  }
  {
    // vectorized h staging: one short8 per thread (row = tid>>4, col = (tid&15)*8)
    short8 hv = *(const short8*)(h + (size_t)bb * 2048 + tid * 8);
    int row = tid >> 4, col = (tid & 15) * 8;
    float* dst = &sh[row * 132 + col];
#pragma unroll
    for (int d = 0; d < 8; ++d) {
      unsigned short u = (unsigned short)hv[d];
      dst[d] = BF2F(*(const bf*)&u);
    }
  }
  if (tid < 240) {
    int idx = bb * 240 + tid;
    float l0 = L[(size_t)idx * 2]     + L[491520 + (size_t)idx * 2]     + rdv(bcRaw, 0, f);
    float l1 = L[(size_t)idx * 2 + 1] + L[491520 + (size_t)idx * 2 + 1] + rdv(bcRaw, 1, f);
    float u0 = rdv(guRaw, idx * 2, f);
    float u1 = rdv(guRaw, idx * 2 + 1, f);
    float g0 = -__logf(-__logf(u0 + 1e-10f) + 1e-10f);
    float g1 = -__logf(-__logf(u1 + 1e-10f) + 1e-10f);
    shw[tid] = fsigmoid(((l1 + g1) - (l0 + g0)) * 2.0f);
  }
  __syncthreads();

  float s = -1e30f;
  if (i < 15) {
    int j = i + (i >= a);
    float d = 0.f;
#pragma unroll
    for (int c = 0; c < 32; ++c) d += sqk[a * 64 + c] * sqk[j * 64 + 32 + c];
    s = shw[a * 15 + i] * d * 0.17677669529663687f;
  }
  float mx = s;
#pragma unroll
  for (int d = 1; d < 16; d <<= 1) mx = fmaxf(mx, __shfl_xor(mx, d));
  float ex = (i < 15) ? __expf(s - mx) : 0.f;
  float sum = ex;
#pragma unroll
  for (int d = 1; d < 16; d <<= 1) sum += __shfl_xor(sum, d);
  float w = (i < 15) ? (ex * frcp(sum)) * shw[a * 15 + i] : 0.f;
  sw[a * 16 + i] = w;
  __syncthreads();

  float ac[8] = {0, 0, 0, 0, 0, 0, 0, 0};
  for (int mm = 0; mm < 15; ++mm) {
    int jm = mm + (mm >= a);
    float wm = sw[a * 16 + mm];
    const float* shp = &sh[jm * 132 + i * 8];
    float4 h0 = *(const float4*)shp;
    float4 h1 = *(const float4*)(shp + 4);
    ac[0] += wm * h0.x; ac[1] += wm * h0.y; ac[2] += wm * h0.z; ac[3] += wm * h0.w;
    ac[4] += wm * h1.x; ac[5] += wm * h1.y; ac[6] += wm * h1.z; ac[7] += wm * h1.w;
  }
  short8 v;
#pragma unroll
  for (int d = 0; d < 8; ++d) {
    bf b = __float2bfloat16(ac[d]);
    v[d] = *(short*)&b;
  }
  *(short8*)&sAgg[a][i * 8] = v;
  __syncthreads();

  // out14 GEMM for this env's 16 rows (wave 0)
  if (tid < 64) {
    const int quad = tid >> 4, ci = tid & 15;
    const int mr = bb * 16;
    float4v acc = {0.f, 0.f, 0.f, 0.f};
#pragma unroll
    for (int ks = 0; ks < 4; ++ks) {
      short8 a_ = *(const short8*)(h + (size_t)(mr + ci) * 128 + ks * 32 + quad * 8);
      short8 b_ = *(const short8*)(W2p + (size_t)ci * 256 + ks * 32 + quad * 8);
      acc = __builtin_amdgcn_mfma_f32_16x16x32_bf16(a_, b_, acc, 0, 0, 0);
    }
#pragma unroll
    for (int ks = 0; ks < 4; ++ks) {
      short8 a_ = *(const short8*)&sAgg[ci][ks * 32 + quad * 8];
      short8 b_ = *(const short8*)(W2p + (size_t)ci * 256 + 128 + ks * 32 + quad * 8);
      acc = __builtin_amdgcn_mfma_f32_16x16x32_bf16(a_, b_, acc, 0, 0, 0);
    }
    if (ci < 14) {
      float bv = rdv(b2Raw, ci, f);
#pragma unroll
      for (int r = 0; r < 4; ++r)
        out[(size_t)(mr + quad * 4 + r) * 14 + ci] = acc[r] + bv;
    }
  }
}

// ---------------------------------------------------------------------------
extern "C" void kernel_launch(void* const* d_in, const int* in_sizes, int n_in,
                              void* d_out, int out_size, void* d_ws, size_t ws_size,
                              hipStream_t stream) {
  const size_t OFF_ARENA = 0;          // bf16 arena; L (3.93MB) overlaps dead
                                       //   inputs+hidden [0, 8.38MB) after kPre
  const size_t OFF_FLAG  = 10220544;
  const size_t OFF_WQK   = 26998016;   // 16 KB
  const size_t OFF_WCB   = 27014400;   // 1 KB
  const size_t OFF_W2P   = 27410944;   // 8 KB
  const size_t OFF_HRNN  = 27419136;   // 4 MB
  const size_t NEEDED    = 84042240;
  if (ws_size < NEEDED) return;
  if (n_in < 23 || in_sizes[0] != 2097152 || in_sizes[3] != 16384 ||
      in_sizes[5] != 49152 || in_sizes[9] != 98304 || in_sizes[17] != 512 ||
      in_sizes[19] != 4096 || in_sizes[21] != 3584 || out_size != 2326528)
    return;

  char* ws = (char*)d_ws;
  bf*    arena = (bf*)(ws + OFF_ARENA);
  float* L     = (float*)(ws + OFF_ARENA);  // 3.93 MB; valid after kPre
  int*   flag  = (int*)(ws + OFF_FLAG);
  bf*    Wqk   = (bf*)(ws + OFF_WQK);
  bf*    Wcb   = (bf*)(ws + OFF_WCB);
  bf*    W2p   = (bf*)(ws + OFF_W2P);
  bf*    hrnn  = (bf*)(ws + OFF_HRNN);

  float* out14 = (float*)d_out;
  float* outh  = (float*)d_out + 229376;

  CArgs ca;
  for (int i = 0; i < 23; ++i) { ca.src[i] = d_in[i]; ca.n[i] = AN[i]; ca.off[i] = AO[i]; }
  kConvert<<<dim3(128, 24), 256, 0, stream>>>(ca, flag, arena,
                                              d_in[19], d_in[20], d_in[21], d_in[17],
                                              Wqk, W2p, Wcb);

  const bf* inputs = arena + AO[0];
  const bf* hidden = arena + AO[1];
  const bf* W1     = arena + AO[3];
  const bf* b1     = arena + AO[4];
  const bf* Wih_c  = arena + AO[5];
  const bf* Whh_c  = arena + AO[6];
  const bf* bih_c  = arena + AO[7];
  const bf* bhh_c  = arena + AO[8];
  const bf* Wih_f  = arena + AO[9];
  const bf* Whh_f  = arena + AO[10];
  const bf* bih_f  = arena + AO[11];
  const bf* bhh_f  = arena + AO[12];
  const bf* Wih_b  = arena + AO[13];
  const bf* Whh_b  = arena + AO[14];
  const bf* bih_b  = arena + AO[15];
  const bf* bhh_b  = arena + AO[16];

  // fused x1 + gi_c + cell GRU (env-local, 1024 blocks)
  kPre<<<dim3(1024), 256, 0, stream>>>(inputs, W1, b1, Wih_c, bih_c, hidden,
                                       Whh_c, bhh_c, hrnn, outh);
  // fused gi-GEMM + 15-step bidirectional GRU -> L (2 dir planes)
  kSeq<<<dim3(1024, 2), 512, 0, stream>>>(hrnn, Wih_f, Wih_b, Whh_f, Whh_b,
                                          bih_f, bih_b, bhh_f, bhh_b, Wcb, L);
  // fused qk + gumbel + attention + out14 GEMM (1024 blocks)
  kTail<<<dim3(1024), 256, 0, stream>>>(hrnn, Wqk, L, d_in[2], d_in[18], flag,
                                        W2p, d_in[22], out14);
}

// Round 12
// 260.638 us; speedup vs baseline: 2.2870x; 1.0153x over previous
//
#include <hip/hip_runtime.h>
#include <hip/hip_bf16.h>

// G2AAgent — ROUND 20: resubmit of R19 (infra failure, no bench data).
//  R19's "MI355X container failed twice" is a broker error — no compile or
//  correctness signal. Source unchanged: best-verified hybrid of R15 kSeq
//  v8 (basic C-init from register-resident gS, nb-adds in epilogue where
//  they overlap the MFMA chain) + R16/R18 kPre/kTail/kConvert.
//  Predicted: kSeq ~114, total ~260, absmax 0.015625. If it lands, both
//  floors are confirmed:
//   - kSeq floor: ~47% VALU (6 irreducible trans/elem, quarter-rate) +
//     20% MFMA + 15 barrier drains; 4 waves/SIMD unified-reg cap (R17).
//   - non-kSeq floor ~146us: three null fusion experiments (R12/R14/R15)
//     => dominated by fixed harness/dispatch overhead, not kernel work.

typedef __attribute__((ext_vector_type(8))) short short8;
typedef __attribute__((ext_vector_type(4))) short short4v;
typedef __attribute__((ext_vector_type(4))) float float4v;

#define BF2F(x) __bfloat162float(x)
typedef __hip_bfloat16 bf;

__device__ __forceinline__ float frcp(float x) {
  return __builtin_amdgcn_rcpf(x);
}
__device__ __forceinline__ float fsigmoid(float x) {
  return frcp(1.f + __expf(-x));
}
__device__ __forceinline__ float ftanh(float x) {
  float e = __expf(2.f * x);
  return 1.f - 2.f * frcp(1.f + e);
}
__device__ __forceinline__ float rdv(const void* p, int i, int f) {
  return f ? ((const float*)p)[i] : BF2F(((const bf*)p)[i]);
}

// ---------------------------------------------------------------------------
static const int AO[23] = {
  0, 2097152, 4194304, 4685824, 4702208, 4702336, 4751488, 4800640, 4801024,
  4801408, 4899712, 4948864, 4949248, 4949632, 5047936, 5097088, 5097472,
  5097856, 5098368, 5098384, 5102480, 5106576, 5110160};
static const int AN[23] = {
  2097152, 2097152, 491520, 16384, 128, 49152, 49152, 384, 384, 98304, 49152,
  384, 384, 98304, 49152, 384, 384, 512, 2, 4096, 4096, 3584, 14};

struct CArgs {
  const void* src[23];
  int n[23];
  int off[23];
};

// ---------------------------------------------------------------------------
// kConvert: per-block self-detect of input dtype; y<23 = vectorized
// normalize into arena (skips 2/18/22); y==23 = prep (Wqk/W2p/Wcb).
__global__ void kConvert(CArgs a, int* __restrict__ flagOut,
                         bf* __restrict__ arena,
                         const void* __restrict__ WqR, const void* __restrict__ WkR,
                         const void* __restrict__ W2R, const void* __restrict__ WcR,
                         bf* __restrict__ Wqk, bf* __restrict__ W2p,
                         bf* __restrict__ Wcb) {
  __shared__ int sflag;
  if (threadIdx.x == 0) sflag = 0;
  __syncthreads();
  {
    const unsigned short* p0 = (const unsigned short*)a.src[0];
    int hit = 0;
    for (int i = threadIdx.x; i < 1024; i += 256) {
      int e = (p0[i] >> 7) & 0xFF;
      if (e >= 0xC0) hit = 1;
    }
    if (hit) atomicOr(&sflag, 1);
  }
  __syncthreads();
  const int f = sflag;
  const int b = blockIdx.y;
  if (b == 0 && blockIdx.x == 0 && threadIdx.x == 0) *flagOut = f;

  if (b == 23) {  // prep
    int idx = blockIdx.x * 256 + threadIdx.x;
    if (idx < 8192) {
      int r = idx >> 7, c = idx & 127;
      float v = (r < 32) ? rdv(WqR, r * 128 + c, f) : rdv(WkR, (r - 32) * 128 + c, f);
      Wqk[idx] = __float2bfloat16(v);
    }
    if (idx < 4096)
      W2p[idx] = __float2bfloat16((idx < 3584) ? rdv(W2R, idx, f) : 0.f);
    if (idx < 512) {
      int dir = idx >> 8, l = (idx >> 7) & 1, k = idx & 127;
      Wcb[idx] = __float2bfloat16(rdv(WcR, l * 256 + dir * 128 + k, f));
    }
    return;
  }
  if (b == 2 || b == 18 || b == 22) return;  // consumed raw via rdv
  const int n = a.n[b];
  const int nv = n & ~7;
  bf* dst = arena + a.off[b];
  const int gid = blockIdx.x * 256 + threadIdx.x;
  const int gs = gridDim.x * 256;
  if (f) {
    const float* s = (const float*)a.src[b];
    for (int i = gid * 8; i < nv; i += gs * 8) {
      float4 x0 = *(const float4*)(s + i);
      float4 x1 = *(const float4*)(s + i + 4);
      short8 v;
      bf t;
      t = __float2bfloat16(x0.x); v[0] = *(short*)&t;
      t = __float2bfloat16(x0.y); v[1] = *(short*)&t;
      t = __float2bfloat16(x0.z); v[2] = *(short*)&t;
      t = __float2bfloat16(x0.w); v[3] = *(short*)&t;
      t = __float2bfloat16(x1.x); v[4] = *(short*)&t;
      t = __float2bfloat16(x1.y); v[5] = *(short*)&t;
      t = __float2bfloat16(x1.z); v[6] = *(short*)&t;
      t = __float2bfloat16(x1.w); v[7] = *(short*)&t;
      *(short8*)(dst + i) = v;
    }
    for (int i = nv + gid; i < n; i += gs) dst[i] = __float2bfloat16(s[i]);
  } else {
    const short8* s = (const short8*)a.src[b];
    short8* d = (short8*)dst;
    for (int i = gid; i * 8 < nv; i += gs) d[i] = s[i];
    const unsigned short* ss = (const unsigned short*)a.src[b];
    unsigned short* ds = (unsigned short*)dst;
    for (int i = nv + gid; i < n; i += gs) ds[i] = ss[i];
  }
}

// ---------------------------------------------------------------------------
// kPre: env-local fusion of x1 + gi_c + cell GRU. 1024 blocks x 16 rows.
__global__ __launch_bounds__(256) void kPre(
    const bf* __restrict__ inputs, const bf* __restrict__ W1,
    const bf* __restrict__ b1, const bf* __restrict__ Wih,
    const bf* __restrict__ bih, const bf* __restrict__ hidden,
    const bf* __restrict__ Whh, const bf* __restrict__ bhh,
    bf* __restrict__ hrnn, float* __restrict__ outh) {
  __shared__ bf sX[16][136];  // x1 tile, 4.25 KB
  const int tid = threadIdx.x;
  const int wave = tid >> 6, lane = tid & 63;
  const int quad = lane >> 4, ci = lane & 15;
  const int row0 = blockIdx.x * 16;

  // stage A: swapped -> D[x1col][row]; wave owns col-tiles {2w, 2w+1}.
  float4v xa[2];
#pragma unroll
  for (int i = 0; i < 2; ++i) xa[i] = {0.f, 0.f, 0.f, 0.f};
#pragma unroll
  for (int ks = 0; ks < 4; ++ks) {
    short8 inr = *(const short8*)(inputs + (size_t)(row0 + ci) * 128 + ks * 32 + quad * 8);
#pragma unroll
    for (int c2 = 0; c2 < 2; ++c2) {
      int ct = wave * 2 + c2;
      short8 wfr = *(const short8*)(W1 + (size_t)(ct * 16 + ci) * 128 + ks * 32 + quad * 8);
      xa[c2] = __builtin_amdgcn_mfma_f32_16x16x32_bf16(wfr, inr, xa[c2], 0, 0, 0);
    }
  }
#pragma unroll
  for (int c2 = 0; c2 < 2; ++c2) {
    int ct = wave * 2 + c2;
    short4v v4;
#pragma unroll
    for (int r = 0; r < 4; ++r) {
      float v = xa[c2][r] + BF2F(b1[ct * 16 + quad * 4 + r]);
      v = fmaxf(v, 0.f);
      bf t = __float2bfloat16(v);
      v4[r] = *(short*)&t;
    }
    *(short4v*)&sX[ci][ct * 16 + quad * 4] = v4;
  }
  __syncthreads();

  short8 af[4];
#pragma unroll
  for (int ks = 0; ks < 4; ++ks)
    af[ks] = *(const short8*)&sX[ci][ks * 32 + quad * 8];

  // stage B: gh + gi, standard D[row][col]; wave owns cols wave*32 + nt*16.
  float4v ah[6], ag[6];
#pragma unroll
  for (int i = 0; i < 6; ++i) { ah[i] = {0.f, 0.f, 0.f, 0.f}; ag[i] = {0.f, 0.f, 0.f, 0.f}; }
#pragma unroll
  for (int ks = 0; ks < 4; ++ks) {
    short8 hr = *(const short8*)(hidden + (size_t)(row0 + ci) * 128 + ks * 32 + quad * 8);
#pragma unroll
    for (int g = 0; g < 3; ++g)
#pragma unroll
      for (int nt = 0; nt < 2; ++nt) {
        int wrow = g * 128 + wave * 32 + nt * 16 + ci;
        short8 bw = *(const short8*)(Whh + (size_t)wrow * 128 + ks * 32 + quad * 8);
        ah[g * 2 + nt] = __builtin_amdgcn_mfma_f32_16x16x32_bf16(hr, bw, ah[g * 2 + nt], 0, 0, 0);
        short8 bi_ = *(const short8*)(Wih + (size_t)wrow * 128 + ks * 32 + quad * 8);
        ag[g * 2 + nt] = __builtin_amdgcn_mfma_f32_16x16x32_bf16(af[ks], bi_, ag[g * 2 + nt], 0, 0, 0);
      }
  }

#pragma unroll
  for (int nt = 0; nt < 2; ++nt) {
    int c = wave * 32 + nt * 16 + ci;
    float biR = BF2F(bih[c]),       bhR = BF2F(bhh[c]);
    float biZ = BF2F(bih[128 + c]), bhZ = BF2F(bhh[128 + c]);
    float biN = BF2F(bih[256 + c]), bhN = BF2F(bhh[256 + c]);
#pragma unroll
    for (int r = 0; r < 4; ++r) {
      int rr = row0 + quad * 4 + r;
      float pre_r = ah[nt][r] + (ag[nt][r] + biR) + bhR;
      float pre_z = ah[2 + nt][r] + (ag[2 + nt][r] + biZ) + bhZ;
      float gnn   = ag[4 + nt][r] + biN;
      float hn_   = ah[4 + nt][r] + bhN;
      float rg = fsigmoid(pre_r);
      float zg = fsigmoid(pre_z);
      float ng = ftanh(gnn + rg * hn_);
      float hp = BF2F(hidden[(size_t)rr * 128 + c]);
      float hv = ng + zg * (hp - ng);
      hrnn[(size_t)rr * 128 + c] = __float2bfloat16(hv);
      outh[(size_t)rr * 128 + c] = hv;
    }
  }
}

// ---------------------------------------------------------------------------
// kSeq v12 (= R15's v8 verbatim): grid (1024, 2), 512 thr = 8 waves,
// (512,4). Operand-swapped MFMAs; fp32 nbr-gi; BASIC C-init (acc=gS/bNc,
// register-resident -> MFMA chain starts immediately); nb adds in the
// EPILOGUE where they overlap the MFMA chain; logit MFMA on wave 0.
__global__ __launch_bounds__(512, 4) void kSeq(
    const bf* __restrict__ hrnn,
    const bf* __restrict__ Wih_f, const bf* __restrict__ Wih_b,
    const bf* __restrict__ Whh_f, const bf* __restrict__ Whh_b,
    const bf* __restrict__ bih_f, const bf* __restrict__ bih_b,
    const bf* __restrict__ bhh_f, const bf* __restrict__ bhh_b,
    const bf* __restrict__ Wcb, float* __restrict__ L) {
  __shared__ float sGiN[16][3][132];            // [batch][gate][hcol] fp32 25.3KB
  __shared__ bf sH[2][16][136];                 // h ping-pong [batch][hcol]
  __shared__ float sL[16][15][2];               // logits [batch][m][logit]
  __shared__ bf sWc[2][136];                    // Wc rows for this dir

  const int env = blockIdx.x;
  const int dir = blockIdx.y;
  const int tid = threadIdx.x;
  const int wave = tid >> 6, lane = tid & 63;
  const int nh = wave;
  const int quad = lane >> 4, ci = lane & 15;
  const bf* Wih = dir ? Wih_b : Wih_f;
  const bf* Whh = dir ? Whh_b : Whh_f;
  const bf* bih = dir ? bih_b : bih_f;
  const bf* bhh = dir ? bhh_b : bhh_f;
  const int h0q = nh * 16 + quad * 4;

  // ---- Phase 1: gi GEMM (swapped: D[hcol][batch]) ----
  float4v gS[3], gN[3];
#pragma unroll
  for (int i = 0; i < 3; ++i) { gS[i] = {0.f, 0.f, 0.f, 0.f}; gN[i] = {0.f, 0.f, 0.f, 0.f}; }
#pragma unroll
  for (int ks = 0; ks < 4; ++ks) {
    short8 bh = *(const short8*)(hrnn + (size_t)(env * 16 + ci) * 128 + ks * 32 + quad * 8);
#pragma unroll
    for (int g = 0; g < 3; ++g) {
      const bf* wrow = Wih + (size_t)(g * 128 + nh * 16 + ci) * 256 + ks * 32 + quad * 8;
      short8 ws = *(const short8*)(wrow);
      short8 wn = *(const short8*)(wrow + 128);
      gS[g] = __builtin_amdgcn_mfma_f32_16x16x32_bf16(ws, bh, gS[g], 0, 0, 0);
      gN[g] = __builtin_amdgcn_mfma_f32_16x16x32_bf16(wn, bh, gN[g], 0, 0, 0);
    }
  }
#pragma unroll
  for (int g = 0; g < 3; ++g)
#pragma unroll
    for (int r = 0; r < 4; ++r) {
      int c = g * 128 + h0q + r;
      float bv = BF2F(bih[c]);
      if (g < 2) bv += BF2F(bhh[c]);
      gS[g][r] += bv;
    }
  // nbr-gi straight to LDS as fp32 (one b128 store per gate)
#pragma unroll
  for (int g = 0; g < 3; ++g)
    *(float4v*)&sGiN[ci][g][h0q] = gN[g];

  {
    bf z = __float2bfloat16(0.f);
    bf* p = &sH[0][0][0];
    for (int i = tid; i < 16 * 136; i += 512) p[i] = z;
    if (tid < 256)
      sWc[tid >> 7][tid & 127] = Wcb[(dir * 2 + (tid >> 7)) * 128 + (tid & 127)];
  }

  // ---- Phase 2: persistent Whh A-frags, constants ----
  short8 Bf[12];
#pragma unroll
  for (int g = 0; g < 3; ++g)
#pragma unroll
    for (int ks = 0; ks < 4; ++ks)
      Bf[g * 4 + ks] =
          *(const short8*)(Whh + (size_t)(g * 128 + nh * 16 + ci) * 128 + ks * 32 + quad * 8);

  float4v bNcV;
#pragma unroll
  for (int r = 0; r < 4; ++r) bNcV[r] = BF2F(bhh[256 + h0q + r]);

  float hPrev[4];
#pragma unroll
  for (int r = 0; r < 4; ++r) hPrev[r] = 0.f;

  __syncthreads();

  // ---- Phase 3: 15 steps ----
  for (int t = 0; t < 15; ++t) {
    const int cur = t & 1, nxt = cur ^ 1;
    const int m = dir ? (14 - t) : t;
    const int jr = m + ((m >= ci) ? 1 : 0);

    float4v nbR = *(const float4v*)&sGiN[jr][0][h0q];
    float4v nbZ = *(const float4v*)&sGiN[jr][1][h0q];
    float4v nbN = *(const float4v*)&sGiN[jr][2][h0q];

    // Basic C-init: MFMA chain carries gS (r,z) and bhh_n; starts from
    // register-resident values immediately (no ds_read dependency).
    float4v acc[3];
    acc[0] = gS[0];
    acc[1] = gS[1];
    acc[2] = bNcV;
    float4v lacc = {0.f, 0.f, 0.f, 0.f};
#pragma unroll
    for (int ks = 0; ks < 4; ++ks) {
      short8 bh = *(const short8*)&sH[cur][ci][ks * 32 + quad * 8];
#pragma unroll
      for (int g = 0; g < 3; ++g)
        acc[g] = __builtin_amdgcn_mfma_f32_16x16x32_bf16(Bf[g * 4 + ks], bh, acc[g], 0, 0, 0);
      if (nh == 0) {
        short8 wv = *(const short8*)&sWc[ci & 1][ks * 32 + quad * 8];
        lacc = __builtin_amdgcn_mfma_f32_16x16x32_bf16(wv, bh, lacc, 0, 0, 0);
      }
    }
    if (nh == 0 && t > 0 && quad == 0) {
      int mp = dir ? (15 - t) : (t - 1);
      sL[ci][mp][0] = lacc[0];
      sL[ci][mp][1] = lacc[1];
    }

    short4v hv4;
#pragma unroll
    for (int r = 0; r < 4; ++r) {
      float pre_r = acc[0][r] + nbR[r];
      float pre_z = acc[1][r] + nbZ[r];
      float gnn   = gS[2][r] + nbN[r];
      float hn_   = acc[2][r];
      float rg = fsigmoid(pre_r);
      float zg = fsigmoid(pre_z);
      float ng = ftanh(gnn + rg * hn_);
      float hv = ng + zg * (hPrev[r] - ng);
      hPrev[r] = hv;
      bf b = __float2bfloat16(hv);
      hv4[r] = *(short*)&b;
    }
    *(short4v*)&sH[nxt][ci][h0q] = hv4;
    __syncthreads();
  }

  if (nh == 0) {
    float4v lacc = {0.f, 0.f, 0.f, 0.f};
#pragma unroll
    for (int ks = 0; ks < 4; ++ks) {
      short8 bh = *(const short8*)&sH[1][ci][ks * 32 + quad * 8];
      short8 wv = *(const short8*)&sWc[ci & 1][ks * 32 + quad * 8];
      lacc = __builtin_amdgcn_mfma_f32_16x16x32_bf16(wv, bh, lacc, 0, 0, 0);
    }
    if (quad == 0) {
      int mf = dir ? 0 : 14;
      sL[ci][mf][0] = lacc[0];
      sL[ci][mf][1] = lacc[1];
    }
  }
  __syncthreads();

  {
    float* Ld = L + (size_t)dir * 491520 + (size_t)env * 480;
    for (int i = tid; i < 480; i += 512) {
      int row = i / 30, rem = i - row * 30;
      int mm = rem >> 1, l = rem & 1;
      Ld[i] = sL[row][mm][l];
    }
  }
}

// ---------------------------------------------------------------------------
// kTail: 1024 blocks x 1 env. qk MFMA + gumbel + attn -> sAgg (LDS),
// then out14 GEMM (wave 0) for this env's 16 rows.
__global__ __launch_bounds__(256) void kTail(
    const bf* __restrict__ h, const bf* __restrict__ Wqk,
    const float* __restrict__ L, const void* __restrict__ guRaw,
    const void* __restrict__ bcRaw, const int* __restrict__ flag,
    const bf* __restrict__ W2p, const void* __restrict__ b2Raw,
    float* __restrict__ out) {
  __shared__ float sh[16 * 132];
  __shared__ float sqk[16 * 64];
  __shared__ float shw[240];
  __shared__ float sw[16 * 16];
  __shared__ bf sAgg[16][136];
  const int bb = blockIdx.x;
  const int tid = threadIdx.x;
  const int f = *flag;
  const int a = tid >> 4, i = tid & 15;

  {
    const int w = tid >> 6, lane = tid & 63;
    const int quad = lane >> 4, ci = lane & 15;
    float4v acc = {0.f, 0.f, 0.f, 0.f};
#pragma unroll
    for (int ks = 0; ks < 4; ++ks) {
      short8 a_ = *(const short8*)(h + (size_t)(bb * 16 + ci) * 128 + ks * 32 + quad * 8);
      short8 b_ = *(const short8*)(Wqk + (size_t)(w * 16 + ci) * 128 + ks * 32 + quad * 8);
      acc = __builtin_amdgcn_mfma_f32_16x16x32_bf16(a_, b_, acc, 0, 0, 0);
    }
#pragma unroll
    for (int r = 0; r < 4; ++r)
      sqk[(quad * 4 + r) * 64 + w * 16 + ci] = acc[r];
  }
  {
    // vectorized h staging: one short8 per thread (row = tid>>4, col = (tid&15)*8)
    short8 hv = *(const short8*)(h + (size_t)bb * 2048 + tid * 8);
    int row = tid >> 4, col = (tid & 15) * 8;
    float* dst = &sh[row * 132 + col];
#pragma unroll
    for (int d = 0; d < 8; ++d) {
      unsigned short u = (unsigned short)hv[d];
      dst[d] = BF2F(*(const bf*)&u);
    }
  }
  if (tid < 240) {
    int idx = bb * 240 + tid;
    float l0 = L[(size_t)idx * 2]     + L[491520 + (size_t)idx * 2]     + rdv(bcRaw, 0, f);
    float l1 = L[(size_t)idx * 2 + 1] + L[491520 + (size_t)idx * 2 + 1] + rdv(bcRaw, 1, f);
    float u0 = rdv(guRaw, idx * 2, f);
    float u1 = rdv(guRaw, idx * 2 + 1, f);
    float g0 = -__logf(-__logf(u0 + 1e-10f) + 1e-10f);
    float g1 = -__logf(-__logf(u1 + 1e-10f) + 1e-10f);
    shw[tid] = fsigmoid(((l1 + g1) - (l0 + g0)) * 2.0f);
  }
  __syncthreads();

  float s = -1e30f;
  if (i < 15) {
    int j = i + (i >= a);
    float d = 0.f;
#pragma unroll
    for (int c = 0; c < 32; ++c) d += sqk[a * 64 + c] * sqk[j * 64 + 32 + c];
    s = shw[a * 15 + i] * d * 0.17677669529663687f;
  }
  float mx = s;
#pragma unroll
  for (int d = 1; d < 16; d <<= 1) mx = fmaxf(mx, __shfl_xor(mx, d));
  float ex = (i < 15) ? __expf(s - mx) : 0.f;
  float sum = ex;
#pragma unroll
  for (int d = 1; d < 16; d <<= 1) sum += __shfl_xor(sum, d);
  float w = (i < 15) ? (ex * frcp(sum)) * shw[a * 15 + i] : 0.f;
  sw[a * 16 + i] = w;
  __syncthreads();

  float ac[8] = {0, 0, 0, 0, 0, 0, 0, 0};
  for (int mm = 0; mm < 15; ++mm) {
    int jm = mm + (mm >= a);
    float wm = sw[a * 16 + mm];
    const float* shp = &sh[jm * 132 + i * 8];
    float4 h0 = *(const float4*)shp;
    float4 h1 = *(const float4*)(shp + 4);
    ac[0] += wm * h0.x; ac[1] += wm * h0.y; ac[2] += wm * h0.z; ac[3] += wm * h0.w;
    ac[4] += wm * h1.x; ac[5] += wm * h1.y; ac[6] += wm * h1.z; ac[7] += wm * h1.w;
  }
  short8 v;
#pragma unroll
  for (int d = 0; d < 8; ++d) {
    bf b = __float2bfloat16(ac[d]);
    v[d] = *(short*)&b;
  }
  *(short8*)&sAgg[a][i * 8] = v;
  __syncthreads();

  // out14 GEMM for this env's 16 rows (wave 0)
  if (tid < 64) {
    const int quad = tid >> 4, ci = tid & 15;
    const int mr = bb * 16;
    float4v acc = {0.f, 0.f, 0.f, 0.f};
#pragma unroll
    for (int ks = 0; ks < 4; ++ks) {
      short8 a_ = *(const short8*)(h + (size_t)(mr + ci) * 128 + ks * 32 + quad * 8);
      short8 b_ = *(const short8*)(W2p + (size_t)ci * 256 + ks * 32 + quad * 8);
      acc = __builtin_amdgcn_mfma_f32_16x16x32_bf16(a_, b_, acc, 0, 0, 0);
    }
#pragma unroll
    for (int ks = 0; ks < 4; ++ks) {
      short8 a_ = *(const short8*)&sAgg[ci][ks * 32 + quad * 8];
      short8 b_ = *(const short8*)(W2p + (size_t)ci * 256 + 128 + ks * 32 + quad * 8);
      acc = __builtin_amdgcn_mfma_f32_16x16x32_bf16(a_, b_, acc, 0, 0, 0);
    }
    if (ci < 14) {
      float bv = rdv(b2Raw, ci, f);
#pragma unroll
      for (int r = 0; r < 4; ++r)
        out[(size_t)(mr + quad * 4 + r) * 14 + ci] = acc[r] + bv;
    }
  }
}

// ---------------------------------------------------------------------------
extern "C" void kernel_launch(void* const* d_in, const int* in_sizes, int n_in,
                              void* d_out, int out_size, void* d_ws, size_t ws_size,
                              hipStream_t stream) {
  const size_t OFF_ARENA = 0;          // bf16 arena; L (3.93MB) overlaps dead
                                       //   inputs+hidden [0, 8.38MB) after kPre
  const size_t OFF_FLAG  = 10220544;
  const size_t OFF_WQK   = 26998016;   // 16 KB
  const size_t OFF_WCB   = 27014400;   // 1 KB
  const size_t OFF_W2P   = 27410944;   // 8 KB
  const size_t OFF_HRNN  = 27419136;   // 4 MB
  const size_t NEEDED    = 84042240;
  if (ws_size < NEEDED) return;
  if (n_in < 23 || in_sizes[0] != 2097152 || in_sizes[3] != 16384 ||
      in_sizes[5] != 49152 || in_sizes[9] != 98304 || in_sizes[17] != 512 ||
      in_sizes[19] != 4096 || in_sizes[21] != 3584 || out_size != 2326528)
    return;

  char* ws = (char*)d_ws;
  bf*    arena = (bf*)(ws + OFF_ARENA);
  float* L     = (float*)(ws + OFF_ARENA);  // 3.93 MB; valid after kPre
  int*   flag  = (int*)(ws + OFF_FLAG);
  bf*    Wqk   = (bf*)(ws + OFF_WQK);
  bf*    Wcb   = (bf*)(ws + OFF_WCB);
  bf*    W2p   = (bf*)(ws + OFF_W2P);
  bf*    hrnn  = (bf*)(ws + OFF_HRNN);

  float* out14 = (float*)d_out;
  float* outh  = (float*)d_out + 229376;

  CArgs ca;
  for (int i = 0; i < 23; ++i) { ca.src[i] = d_in[i]; ca.n[i] = AN[i]; ca.off[i] = AO[i]; }
  kConvert<<<dim3(128, 24), 256, 0, stream>>>(ca, flag, arena,
                                              d_in[19], d_in[20], d_in[21], d_in[17],
                                              Wqk, W2p, Wcb);

  const bf* inputs = arena + AO[0];
  const bf* hidden = arena + AO[1];
  const bf* W1     = arena + AO[3];
  const bf* b1     = arena + AO[4];
  const bf* Wih_c  = arena + AO[5];
  const bf* Whh_c  = arena + AO[6];
  const bf* bih_c  = arena + AO[7];
  const bf* bhh_c  = arena + AO[8];
  const bf* Wih_f  = arena + AO[9];
  const bf* Whh_f  = arena + AO[10];
  const bf* bih_f  = arena + AO[11];
  const bf* bhh_f  = arena + AO[12];
  const bf* Wih_b  = arena + AO[13];
  const bf* Whh_b  = arena + AO[14];
  const bf* bih_b  = arena + AO[15];
  const bf* bhh_b  = arena + AO[16];

  // fused x1 + gi_c + cell GRU (env-local, 1024 blocks)
  kPre<<<dim3(1024), 256, 0, stream>>>(inputs, W1, b1, Wih_c, bih_c, hidden,
                                       Whh_c, bhh_c, hrnn, outh);
  // fused gi-GEMM + 15-step bidirectional GRU -> L (2 dir planes)
  kSeq<<<dim3(1024, 2), 512, 0, stream>>>(hrnn, Wih_f, Wih_b, Whh_f, Whh_b,
                                          bih_f, bih_b, bhh_f, bhh_b, Wcb, L);
  // fused qk + gumbel + attention + out14 GEMM (1024 blocks)
  kTail<<<dim3(1024), 256, 0, stream>>>(hrnn, Wqk, L, d_in[2], d_in[18], flag,
                                        W2p, d_in[22], out14);
}